// Round 6
// baseline (606.204 us; speedup 1.0000x reference)
//
#include <hip/hip_runtime.h>

#define NC 19
#define NB 10
#define NCELL (NC * NB)            // 190
#define NPART (3 * NCELL + 2 * NC) // 608: conf[190] pred[190] acc[190] psum[19] inval[19]
#define REP 4
#define NSLOT 32                   // global accumulator replicas
#define TPB 256
#define TILE 256                   // pixels per block-tile
#define WTILE 64                   // pixels per wave-tile (one lane each)
#define NROWS (NC + 1)             // 19 class rows + 1 target row
#define BLOCKS 512                 // 8192 tiles / 512 = 16 per block, exact

// global -> LDS direct, 4B/lane (one 256B row per instruction).
// LDS dest is wave-uniform; HW writes lane*4 bytes.
__device__ __forceinline__ void load4_lds(const void* g, void* l) {
    auto* gp = reinterpret_cast<const unsigned int __attribute__((address_space(1)))*>(
        reinterpret_cast<uintptr_t>(g));
    auto* lp = reinterpret_cast<unsigned int __attribute__((address_space(3)))*>(
        reinterpret_cast<uintptr_t>(l));
    __builtin_amdgcn_global_load_lds(gp, lp, 4, 0, 0);
}

// ---------------------------------------------------------------------------
// Pass 1: wave-private LDS pipelines, ZERO barriers in the main loop.
// Each wave owns a 64-px column slice of each tile: 20 rows x 256B staged by
// 20 global_load_lds, double-buffered, self-paced counted s_waitcnt vmcnt(20).
// Waves desynchronize -> no block-wide drain convoy (the round-4 killer).
// Inner loop is BRANCH-FREE: unconditional ds_add with address cndmask'd to a
// per-thread dump cell when bin==0 (bin-0 recovered in pass2 by subtraction):
//   pred(c,0) = valid(c) - sum_{b>=1} pred(c,b)
//   conf(c,0) = psum(c)  - sum_{b>=1} conf(c,b)
// ---------------------------------------------------------------------------
__global__ __launch_bounds__(TPB) void cce_pass1(
    const float* __restrict__ logits, const int* __restrict__ tgt,
    float* __restrict__ gacc, int hw)
{
    constexpr int O_CONF = 0;
    constexpr int O_PRED = REP * NCELL;                 // 760
    constexpr int O_ACC  = 2 * REP * NCELL;             // 1520
    constexpr int O_PSUM = 3 * REP * NCELL;             // 2280
    constexpr int O_INV  = O_PSUM + REP * NC;           // 2356
    constexpr int O_DUMP = O_INV + NC;                  // 2375
    constexpr int LDS_N  = O_DUMP + TPB;                // 2631 floats = 10.5 KB

    __shared__ float wbuf[4][2][NROWS][WTILE];          // 40 KB (per-wave dbuf)
    __shared__ float hist[LDS_N];

    for (int i = threadIdx.x; i < LDS_N; i += TPB) hist[i] = 0.0f;
    __syncthreads();

    const int lane = threadIdx.x & 63;
    const int wv   = threadIdx.x >> 6;
    const int rep  = lane & (REP - 1);
    const int dl   = O_DUMP + threadIdx.x;              // per-thread dump cell

    float psum[NC];
#pragma unroll
    for (int c = 0; c < NC; ++c) psum[c] = 0.0f;

    const int ntiles = hw / TILE;                       // 8192
    const int nt     = (ntiles + (int)gridDim.x - 1) / (int)gridDim.x; // 16
    const int start  = (int)blockIdx.x * nt;
    const int end    = (start + nt) < ntiles ? (start + nt) : ntiles;

    auto stage = [&](int b, int t) {
#pragma unroll
        for (int rr = 0; rr < NROWS; ++rr) {
            const void* g = (rr < NC)
                ? (const void*)(logits + (size_t)rr * hw + (size_t)t * TILE + wv * WTILE + lane)
                : (const void*)(tgt + (size_t)t * TILE + wv * WTILE + lane);
            load4_lds(g, (void*)&wbuf[wv][b][rr][0]);
        }
    };

    int cur = 0;
    if (start < end) stage(0, start);

    for (int t = start; t < end; ++t) {
        if (t + 1 < end) {
            stage(cur ^ 1, t + 1);                      // 20 more in flight (40 total)
            asm volatile("s_waitcnt vmcnt(20)" ::: "memory"); // oldest 20 (tile t) done
        } else {
            asm volatile("s_waitcnt vmcnt(0)" ::: "memory");
        }
        __builtin_amdgcn_sched_barrier(0);

        float x[NC];
#pragma unroll
        for (int c = 0; c < NC; ++c) x[c] = wbuf[wv][cur][c][lane];
        const int tg = ((const int*)&wbuf[wv][cur][NC][0])[lane];

        float m = x[0];
#pragma unroll
        for (int c = 1; c < NC; ++c) m = fmaxf(m, x[c]);
        float s = 0.0f;
#pragma unroll
        for (int c = 0; c < NC; ++c) { x[c] = __expf(x[c] - m); s += x[c]; }
        const float r = __builtin_amdgcn_rcpf(s);

        float pt = 0.0f, pmin = 1.0f;
#pragma unroll
        for (int c = 0; c < NC; ++c) {
            const float p = x[c] * r;
            psum[c] += p;
            pt   = (c == tg) ? p : pt;                  // cndmask (c is imm)
            pmin = fminf(pmin, p);
            int bb = (int)ceilf(p * 10.0f) - 1;         // p<=0.1 -> bb<=0
            const bool hot = bb > 0;                    // bin >= 1
            bb = bb > NB - 1 ? NB - 1 : bb;
            const int cell = rep * NCELL + c * NB + bb;
            atomicAdd(&hist[hot ? O_CONF + cell : dl], p);     // branch-free
            atomicAdd(&hist[hot ? O_PRED + cell : dl], 1.0f);
        }
        int bt = (int)ceilf(pt * 10.0f) - 1;
        bt = bt < 0 ? 0 : (bt > NB - 1 ? NB - 1 : bt);
        atomicAdd(&hist[(pt > 0.0f) ? O_ACC + rep * NCELL + tg * NB + bt : dl], 1.0f);

        if (!(pmin > 0.0f)) {                           // ultra-rare underflow
#pragma unroll
            for (int c = 0; c < NC; ++c)
                if (!(x[c] * r > 0.0f)) atomicAdd(&hist[O_INV + c], 1.0f);
        }
        cur ^= 1;
    }

#pragma unroll
    for (int c = 0; c < NC; ++c)
        atomicAdd(&hist[O_PSUM + rep * NC + c], psum[c]);
    __syncthreads();

    // Reduce replicas; flush block partials to one of NSLOT global slot sets.
    float* slot = gacc + (size_t)(blockIdx.x & (NSLOT - 1)) * NPART;
    for (int j = threadIdx.x; j < NPART; j += TPB) {
        float v = 0.0f;
        if (j < NCELL) {
            for (int rr = 0; rr < REP; ++rr) v += hist[O_CONF + rr * NCELL + j];
        } else if (j < 2 * NCELL) {
            for (int rr = 0; rr < REP; ++rr) v += hist[O_PRED + rr * NCELL + (j - NCELL)];
        } else if (j < 3 * NCELL) {
            for (int rr = 0; rr < REP; ++rr) v += hist[O_ACC + rr * NCELL + (j - 2 * NCELL)];
        } else if (j < 3 * NCELL + NC) {
            for (int rr = 0; rr < REP; ++rr) v += hist[O_PSUM + rr * NC + (j - 3 * NCELL)];
        } else {
            v = hist[O_INV + (j - 3 * NCELL - NC)];
        }
        atomicAdd(&slot[j], v);
    }
}

// ---------------------------------------------------------------------------
// Pass 2: sum NSLOT slots, bin-0 corrections, 190-cell loss (double).
// slot layout: [0,190) conf, [190,380) pred, [380,570) acc, [570,589) psum,
//              [589,608) inval.
// ---------------------------------------------------------------------------
__global__ void cce_pass2(const float* __restrict__ gacc, float* __restrict__ out, int hw)
{
    __shared__ double fin[NPART];
    const int j = threadIdx.x; // blockDim = 640
    if (j < NPART) {
        double v = 0.0;
        for (int s = 0; s < NSLOT; ++s) v += (double)gacc[(size_t)s * NPART + j];
        fin[j] = v;
    }
    __syncthreads();

    if (j < NC) {
        double spred = 0.0, sconf = 0.0;
        for (int b = 1; b < NB; ++b) {
            spred += fin[NCELL + j * NB + b];
            sconf += fin[j * NB + b];
        }
        const double validc = (double)hw - fin[3 * NCELL + NC + j];
        fin[NCELL + j * NB] = validc - spred;             // pred(c,0)
        fin[j * NB]         = fin[3 * NCELL + j] - sconf; // conf(c,0)
    }
    __syncthreads();

    if (j < 64) {
        double tot = 0.0;
        for (int c = j; c < NCELL; c += 64) tot += fin[NCELL + c];
#pragma unroll
        for (int o = 32; o > 0; o >>= 1) tot += __shfl_down(tot, o);
        tot = __shfl(tot, 0);

        double loss = 0.0;
        for (int c = j; c < NCELL; c += 64) {
            const double pred = fin[NCELL + c];
            const double conf = fin[c];
            const double acc  = fin[2 * NCELL + c];
            const double d    = (acc - conf) / (pred + 1e-13);
            loss += d * d * (pred / tot);
        }
#pragma unroll
        for (int o = 32; o > 0; o >>= 1) loss += __shfl_down(loss, o);
        if (j == 0) out[0] = (float)loss;
    }
}

extern "C" void kernel_launch(void* const* d_in, const int* in_sizes, int n_in,
                              void* d_out, int out_size, void* d_ws, size_t ws_size,
                              hipStream_t stream)
{
    const float* logits = (const float*)d_in[0];
    const int*   tgt    = (const int*)d_in[1];
    float*       gacc   = (float*)d_ws;
    const int    hw     = in_sizes[1]; // 1024*2048

    hipMemsetAsync(gacc, 0, (size_t)NSLOT * NPART * sizeof(float), stream);
    cce_pass1<<<BLOCKS, TPB, 0, stream>>>(logits, tgt, gacc, hw);
    cce_pass2<<<1, 640, 0, stream>>>(gacc, (float*)d_out, hw);
}

// Round 7
// 267.748 us; speedup vs baseline: 2.2641x; 2.2641x over previous
//
#include <hip/hip_runtime.h>

#define NC 19
#define NB 10
#define NCELL (NC * NB)            // 190
#define NPART (3 * NCELL + 2 * NC) // 608: conf[190] pred[190] acc[190] psum[19] inval[19]
#define REP 16                     // LDS histogram replicas (lane & 15)
#define NSLOT 32                   // global accumulator replicas
#define TPB 256
#define BLOCKS 768                 // 3 blocks/CU

typedef float f32x4 __attribute__((ext_vector_type(4)));

// ---------------------------------------------------------------------------
// Pass 1: register-tile softmax + binned accumulation.
// Per 4-px group: 19 global_load_dwordx4 issued via inline asm (compiler
// CANNOT sink/serialize them), one vmcnt(0) with "+v" ties on all 19 dests
// (later uses are data-dependent on the wait -> no scheduler hoisting).
// Latency hidden by TLP: no barriers, 12 waves/CU.
// REP=16 lane-sharded LDS hist -> worst same-address collision 4-way.
// Bin-0 (~87% of entries) recovered in pass2 by subtraction:
//   pred(c,0) = valid(c) - sum_{b>=1} pred(c,b)
//   conf(c,0) = psum(c)  - sum_{b>=1} conf(c,b)
// ---------------------------------------------------------------------------
__global__ __launch_bounds__(TPB, 3) void cce_pass1(
    const float* __restrict__ logits, const int* __restrict__ tgt,
    float* __restrict__ gacc, int hw)
{
    constexpr int O_CONF = 0;
    constexpr int O_PRED = REP * NCELL;                 // 3040
    constexpr int O_ACC  = 2 * REP * NCELL;             // 6080
    constexpr int O_PSUM = 3 * REP * NCELL;             // 9120
    constexpr int O_INV  = O_PSUM + REP * NC;           // 9424
    constexpr int LDS_N  = O_INV + NC;                  // 9443 floats = 37.8 KB

    __shared__ float hist[LDS_N];
    for (int i = threadIdx.x; i < LDS_N; i += TPB) hist[i] = 0.0f;
    __syncthreads();

    const int rep = threadIdx.x & (REP - 1);
    float psum[NC];
#pragma unroll
    for (int c = 0; c < NC; ++c) psum[c] = 0.0f;

    const int ngr      = hw >> 2;                       // float4 groups
    const int tid      = blockIdx.x * TPB + threadIdx.x;
    const int nthreads = (int)gridDim.x * TPB;

    for (int g = tid; g < ngr; g += nthreads) {
        const unsigned voff = (unsigned)g * 16u;
        f32x4 xv[19];
        // 19 independent 16B loads, forced back-to-back in issue order.
#define LD(i) asm volatile("global_load_dwordx4 %0, %1, %2"                      \
                           : "=v"(xv[i])                                          \
                           : "v"(voff), "s"(logits + (size_t)(i) * hw));
        LD(0) LD(1) LD(2) LD(3) LD(4) LD(5) LD(6) LD(7) LD(8) LD(9)
        LD(10) LD(11) LD(12) LD(13) LD(14) LD(15) LD(16) LD(17) LD(18)
#undef LD
        const int4 tq = *reinterpret_cast<const int4*>(tgt + 4 * (size_t)g);
        // Wait for all 19; "+v" ties make every later xv use depend on this asm.
        asm volatile("s_waitcnt vmcnt(0)"
                     : "+v"(xv[0]), "+v"(xv[1]), "+v"(xv[2]), "+v"(xv[3]),
                       "+v"(xv[4]), "+v"(xv[5]), "+v"(xv[6]), "+v"(xv[7]),
                       "+v"(xv[8]), "+v"(xv[9]), "+v"(xv[10]), "+v"(xv[11]),
                       "+v"(xv[12]), "+v"(xv[13]), "+v"(xv[14]), "+v"(xv[15]),
                       "+v"(xv[16]), "+v"(xv[17]), "+v"(xv[18])
                     :: "memory");

#pragma unroll
        for (int k = 0; k < 4; ++k) {
            const int tgk = (k == 0) ? tq.x : (k == 1) ? tq.y : (k == 2) ? tq.z : tq.w;

            float m = xv[0][k];
#pragma unroll
            for (int c = 1; c < NC; ++c) m = fmaxf(m, xv[c][k]);
            float s = 0.0f;
#pragma unroll
            for (int c = 0; c < NC; ++c) { xv[c][k] = __expf(xv[c][k] - m); s += xv[c][k]; }
            const float r = __builtin_amdgcn_rcpf(s);

            float pt = 0.0f, pmin = 1.0f;
#pragma unroll
            for (int c = 0; c < NC; ++c) {
                const float p = xv[c][k] * r;
                psum[c] += p;
                pt   = (c == tgk) ? p : pt;             // cndmask (c is imm)
                pmin = fminf(pmin, p);
                int bb = (int)ceilf(p * 10.0f) - 1;     // p<=0.1 -> bb<=0
                if (bb > 0) {                           // hot: bin >= 1 (~13%)
                    bb = bb > NB - 1 ? NB - 1 : bb;
                    atomicAdd(&hist[O_CONF + rep * NCELL + c * NB + bb], p);
                    atomicAdd(&hist[O_PRED + rep * NCELL + c * NB + bb], 1.0f);
                }
            }
            if (pt > 0.0f) {                            // no_acc: 1 atomic/px
                int bt = (int)ceilf(pt * 10.0f) - 1;
                bt = bt < 0 ? 0 : (bt > NB - 1 ? NB - 1 : bt);
                atomicAdd(&hist[O_ACC + rep * NCELL + tgk * NB + bt], 1.0f);
            }
            if (!(pmin > 0.0f)) {                       // ultra-rare underflow
#pragma unroll
                for (int c = 0; c < NC; ++c)
                    if (!(xv[c][k] * r > 0.0f)) atomicAdd(&hist[O_INV + c], 1.0f);
            }
        }
    }

#pragma unroll
    for (int c = 0; c < NC; ++c)
        atomicAdd(&hist[O_PSUM + rep * NC + c], psum[c]);
    __syncthreads();

    // Reduce replicas; flush block partials to one of NSLOT global slot sets.
    float* slot = gacc + (size_t)(blockIdx.x & (NSLOT - 1)) * NPART;
    for (int j = threadIdx.x; j < NPART; j += TPB) {
        float v = 0.0f;
        if (j < NCELL) {
            for (int rr = 0; rr < REP; ++rr) v += hist[O_CONF + rr * NCELL + j];
        } else if (j < 2 * NCELL) {
            for (int rr = 0; rr < REP; ++rr) v += hist[O_PRED + rr * NCELL + (j - NCELL)];
        } else if (j < 3 * NCELL) {
            for (int rr = 0; rr < REP; ++rr) v += hist[O_ACC + rr * NCELL + (j - 2 * NCELL)];
        } else if (j < 3 * NCELL + NC) {
            for (int rr = 0; rr < REP; ++rr) v += hist[O_PSUM + rr * NC + (j - 3 * NCELL)];
        } else {
            v = hist[O_INV + (j - 3 * NCELL - NC)];
        }
        atomicAdd(&slot[j], v);
    }
}

// ---------------------------------------------------------------------------
// Pass 2: sum NSLOT slots, bin-0 corrections, 190-cell loss (double).
// slot layout: [0,190) conf, [190,380) pred, [380,570) acc, [570,589) psum,
//              [589,608) inval.
// ---------------------------------------------------------------------------
__global__ void cce_pass2(const float* __restrict__ gacc, float* __restrict__ out, int hw)
{
    __shared__ double fin[NPART];
    const int j = threadIdx.x; // blockDim = 640
    if (j < NPART) {
        double v = 0.0;
        for (int s = 0; s < NSLOT; ++s) v += (double)gacc[(size_t)s * NPART + j];
        fin[j] = v;
    }
    __syncthreads();

    if (j < NC) {
        double spred = 0.0, sconf = 0.0;
        for (int b = 1; b < NB; ++b) {
            spred += fin[NCELL + j * NB + b];
            sconf += fin[j * NB + b];
        }
        const double validc = (double)hw - fin[3 * NCELL + NC + j];
        fin[NCELL + j * NB] = validc - spred;             // pred(c,0)
        fin[j * NB]         = fin[3 * NCELL + j] - sconf; // conf(c,0)
    }
    __syncthreads();

    if (j < 64) {
        double tot = 0.0;
        for (int c = j; c < NCELL; c += 64) tot += fin[NCELL + c];
#pragma unroll
        for (int o = 32; o > 0; o >>= 1) tot += __shfl_down(tot, o);
        tot = __shfl(tot, 0);

        double loss = 0.0;
        for (int c = j; c < NCELL; c += 64) {
            const double pred = fin[NCELL + c];
            const double conf = fin[c];
            const double acc  = fin[2 * NCELL + c];
            const double d    = (acc - conf) / (pred + 1e-13);
            loss += d * d * (pred / tot);
        }
#pragma unroll
        for (int o = 32; o > 0; o >>= 1) loss += __shfl_down(loss, o);
        if (j == 0) out[0] = (float)loss;
    }
}

extern "C" void kernel_launch(void* const* d_in, const int* in_sizes, int n_in,
                              void* d_out, int out_size, void* d_ws, size_t ws_size,
                              hipStream_t stream)
{
    const float* logits = (const float*)d_in[0];
    const int*   tgt    = (const int*)d_in[1];
    float*       gacc   = (float*)d_ws;
    const int    hw     = in_sizes[1]; // 1024*2048

    hipMemsetAsync(gacc, 0, (size_t)NSLOT * NPART * sizeof(float), stream);
    cce_pass1<<<BLOCKS, TPB, 0, stream>>>(logits, tgt, gacc, hw);
    cce_pass2<<<1, 640, 0, stream>>>(gacc, (float*)d_out, hw);
}